// Round 10
// baseline (372.741 us; speedup 1.0000x reference)
//
#include <hip/hip_runtime.h>
#include <math.h>

#define HID 50
#define TT  512
#define BT  16      // batch per block (= MFMA N)
#define NCW 4       // compute waves (13 tiles: 3,3,3,4); wave0 also does chores
#define HS  72      // H plane row stride in shorts
#define L2E 1.44269504088896f

typedef __attribute__((ext_vector_type(8))) short bf16x8;
typedef __attribute__((ext_vector_type(4))) float f32x4;

__device__ __forceinline__ unsigned short bf16_rtne(float f) {
    unsigned u = __float_as_uint(f);
    u = (u + 0x7FFFu + ((u >> 16) & 1u)) >> 16;
    return (unsigned short)u;
}
__device__ __forceinline__ float bf16_f32(unsigned short s) {
    return __uint_as_float(((unsigned)s) << 16);
}

// Block = 256 threads (4 waves = 1/SIMD), BT=16 batch, grid 256 = 1 block/CU.
// R9 structure: minimal wave count -> no same-SIMD trans-pipe contention, a
// 4-wave barrier convoy, ILP from 3-4 independent tiles per wave.
// A rows are PRE-SCALED by log2e (i,f,o) / 2*log2e (g) so exp2 eats preacts
// directly; activations use the fused forms
//   sig(i)*tanh(g) = (Eg-1)*rcp((1+Ei)(1+Eg)),  h = (Ec-1)*rcp((1+Eo)(1+Ec))
// -> 8 trans per unit (5 exp2 + 3 rcp) instead of 10.
// K-slots: 0..49 = s*W_hh | 50 = (s*Wih)_hi (x_hi) | 51 = (s*bias)_hi (1.0)
//          52 = (s*Wih)_hi (x_lo) | 53 = (s*bias)_lo (1.0) | 54 = (s*Wih)_lo (x_hi)
__global__ __launch_bounds__(256) void lstm_mfma7_kernel(
    const float* __restrict__ x,      // [B, T]
    const float* __restrict__ W_ih,   // [200, 1]
    const float* __restrict__ W_hh,   // [200, 50]
    const float* __restrict__ b_ih,   // [200]
    const float* __restrict__ b_hh,   // [200]
    const float* __restrict__ W_out,  // [1, 50]
    const float* __restrict__ b_out,  // [1]
    float* __restrict__ out)          // [B, T]
{
    const int tid  = threadIdx.x;
    const int lane = tid & 63;
    const int wv   = tid >> 6;       // 0..3
    const int col  = lane & 15;      // A-m / B-n(batch) / D-col(batch)
    const int quad = lane >> 4;      // k-octet / D row-group

    __shared__ __align__(16) unsigned short Hh[2][BT][HS];
    __shared__ float ypart[2][NCW][17];

    // zero both H buffers (k-slots 55..63 + pads stay 0)
    for (int i = tid; i < 2 * BT * HS; i += 256)
        (&Hh[0][0][0])[i] = 0;

    const int base = wv * 3;                    // first tile
    const int cnt  = 3 + (wv == 3 ? 1 : 0);     // tiles owned {3,3,3,4}

    // persistent A fragments (single plane, pre-scaled rows)
    bf16x8 Ah[4][2];
    float c[4]  = {0.f, 0.f, 0.f, 0.f};
    float wo[4] = {0.f, 0.f, 0.f, 0.f};
    #pragma unroll
    for (int i = 0; i < 4; ++i) {
        #pragma unroll
        for (int kk = 0; kk < 2; ++kk)
            #pragma unroll
            for (int j = 0; j < 8; ++j) Ah[i][kk][j] = 0;
        if (i < cnt) {
            const int gh  = (base + i) * 16 + col;   // g^ row
            const int u   = gh >> 2;
            const int ty  = gh & 3;
            const bool vl = (u < HID);
            const int og  = ty * HID + u;            // original gate row
            const float sc = (ty == 2) ? 2.f * L2E : L2E;  // g-rows get 2*log2e
            #pragma unroll
            for (int kk = 0; kk < 2; ++kk) {
                #pragma unroll
                for (int j = 0; j < 8; ++j) {
                    const int k = kk * 32 + quad * 8 + j;
                    float v = 0.f;
                    if (vl) {
                        if (k < HID)      v = sc * W_hh[og * HID + k];
                        else if (k == 50) v = sc * W_ih[og];
                        else if (k == 51) v = sc * (b_ih[og] + b_hh[og]);
                        else if (k == 52) v = sc * W_ih[og];
                        else if (k == 53) {
                            const float sb = sc * (b_ih[og] + b_hh[og]);
                            v = sb - bf16_f32(bf16_rtne(sb));
                        } else if (k == 54) {
                            const float sw = sc * W_ih[og];
                            v = sw - bf16_f32(bf16_rtne(sw));
                        }
                    }
                    Ah[i][kk][j] = (short)bf16_rtne(v);
                }
            }
            const int uu = (base + i) * 4 + quad;
            wo[i] = (uu < HID) ? W_out[uu] : 0.f;
        }
    }
    const float bo = b_out[0];
    float* yout = out + (size_t)blockIdx.x * BT * TT;

    // chore x pipeline (wave0 lanes 16..31 own batch b = lane-16)
    const int bx = (lane >= 16 && lane < 32) ? (lane - 16) : 0;
    const float* xrow = x + (size_t)(blockIdx.x * BT + bx) * TT;
    float xa = 0.f;
    if (wv == 0 && lane >= 16 && lane < 32)
        xa = xrow[1];                            // x[b][1], written during t=0

    __syncthreads();    // zeroed H visible

    // buffer-0 slots for t=0: x_0 hi/lo + 1.0 markers (packed b32 writes)
    if (tid < BT) {
        const float x0 = x[(size_t)(blockIdx.x * BT + tid) * TT];
        const unsigned short hx = bf16_rtne(x0);
        const unsigned short lx = bf16_rtne(x0 - bf16_f32(hx));
        unsigned* row32 = (unsigned*)&Hh[0][tid][0];
        row32[25] = (unsigned)hx | (0x3F80u << 16);   // k=50,51
        row32[26] = (unsigned)lx | (0x3F80u << 16);   // k=52,53
        Hh[0][tid][54] = hx;                          // k=54
    }
    __syncthreads();

    for (int t = 0; t < TT; ++t) {
        const int p = t & 1;        // read buffer; write 1-p

        if (wv == 0) {
            // ---- chores folded into wave0 (3 tiles, vs wave3's 4) ----
            if (lane < 16) {
                if (t > 0) {        // y_{t-1}: reduce + global store (early)
                    float s = bo;
                    #pragma unroll
                    for (int w = 0; w < NCW; ++w) s += ypart[1 - p][w][lane];
                    yout[(size_t)lane * TT + (t - 1)] = s;
                }
            } else if (lane < 32) { // x_{t+1} slots from register, prefetch t+2
                const int b = lane - 16;
                const unsigned short hx = bf16_rtne(xa);
                const unsigned short lx = bf16_rtne(xa - bf16_f32(hx));
                unsigned* row32 = (unsigned*)&Hh[1 - p][b][0];
                row32[25] = (unsigned)hx | (0x3F80u << 16);
                row32[26] = (unsigned)lx | (0x3F80u << 16);
                Hh[1 - p][b][54] = hx;
                xa = xrow[(t + 2 < TT) ? t + 2 : TT - 1];
            }
        }

        // ---- compute (all 4 waves) ----
        const unsigned short* hrow = &Hh[p][col][0];
        const bf16x8 B0 = *(const bf16x8*)&hrow[quad * 8];
        const bf16x8 B1 = *(const bf16x8*)&hrow[32 + quad * 8];

        float psum = 0.f;
        #pragma unroll
        for (int i = 0; i < 4; ++i) {
            if (i < cnt) {
                f32x4 acc = {0.f, 0.f, 0.f, 0.f};
                acc = __builtin_amdgcn_mfma_f32_16x16x32_bf16(Ah[i][0], B0, acc, 0, 0, 0);
                acc = __builtin_amdgcn_mfma_f32_16x16x32_bf16(Ah[i][1], B1, acc, 0, 0, 0);
                // acc = scaled preacts {i', f', g', o'} of unit u, batch col
                const int u = (base + i) * 4 + quad;
                const float Ei = __builtin_amdgcn_exp2f(-acc.x);
                const float Ef = __builtin_amdgcn_exp2f(-acc.y);
                const float Eg = __builtin_amdgcn_exp2f(acc.z);
                const float Eo = __builtin_amdgcn_exp2f(-acc.w);
                const float sf = __builtin_amdgcn_rcpf(1.f + Ef);
                const float P  = (Eg - 1.f) *
                                 __builtin_amdgcn_rcpf((1.f + Ei) * (1.f + Eg));
                c[i] = fmaf(sf, c[i], P);                    // c_t
                const float Ec = __builtin_amdgcn_exp2f(2.f * L2E * c[i]);
                const float h  = (Ec - 1.f) *
                                 __builtin_amdgcn_rcpf((1.f + Eo) * (1.f + Ec));
                if (u < HID)
                    Hh[1 - p][col][u] = bf16_rtne(h);
                psum = fmaf(h, wo[i], psum);                 // phantom wo = 0
            }
        }
        // per-wave y partial: sum over quad groups
        psum += __shfl_xor(psum, 16);
        psum += __shfl_xor(psum, 32);
        if (lane < 16) ypart[p][wv][lane] = psum;

        __syncthreads();    // the ONE barrier
    }

    // epilogue: y_{TT-1}
    if (wv == 0 && lane < 16) {
        float s = bo;
        #pragma unroll
        for (int w = 0; w < NCW; ++w) s += ypart[(TT - 1) & 1][w][lane];
        yout[(size_t)lane * TT + (TT - 1)] = s;
    }
}

extern "C" void kernel_launch(void* const* d_in, const int* in_sizes, int n_in,
                              void* d_out, int out_size, void* d_ws, size_t ws_size,
                              hipStream_t stream) {
    const float* x     = (const float*)d_in[0];
    const float* W_ih  = (const float*)d_in[1];
    const float* W_hh  = (const float*)d_in[2];
    const float* b_ih  = (const float*)d_in[3];
    const float* b_hh  = (const float*)d_in[4];
    const float* W_out = (const float*)d_in[5];
    const float* b_out = (const float*)d_in[6];
    float* out = (float*)d_out;

    const int B = in_sizes[0] / TT;          // 4096
    lstm_mfma7_kernel<<<B / BT, 256, 0, stream>>>(x, W_ih, W_hh, b_ih, b_hh,
                                                  W_out, b_out, out);
}